// Round 1
// baseline (2547.530 us; speedup 1.0000x reference)
//
#include <hip/hip_runtime.h>
#include <hip/hip_bf16.h>
#include <math.h>

#define TM 64

// ---------------- fused FFN + decoder: coords -> emb, writes x = [features, emb] ----------------
__global__ __launch_bounds__(256) void ffn_kernel(
    const float* __restrict__ coords, const float* __restrict__ features,
    const float* __restrict__ fw0, const float* __restrict__ fb0,
    const float* __restrict__ fg0, const float* __restrict__ fe0,
    const float* __restrict__ fw1, const float* __restrict__ fb1,
    const float* __restrict__ fg1, const float* __restrict__ fe1,
    const float* __restrict__ fw2, const float* __restrict__ fb2,
    const float* __restrict__ fg2, const float* __restrict__ fe2,
    const float* __restrict__ fw3, const float* __restrict__ fb3,
    const float* __restrict__ dw0, const float* __restrict__ db0,
    const float* __restrict__ dw1, const float* __restrict__ db1,
    const float* __restrict__ dw2, const float* __restrict__ db2,
    float* __restrict__ xout, int n_nodes)
{
    __shared__ float hbuf[2][128][TM];   // [feature][node], ping-pong, 64 KB
    __shared__ float wl[128 * 128];      // staged layer weights, 64 KB

    const int t  = threadIdx.x;
    const int tx = t & 15;   // 16 out-groups
    const int ty = t >> 4;   // 16 node-groups of 4
    const int n4 = ty * 4;
    const int n0 = blockIdx.x * TM;

    const int jA = tx * 4;        // outs jA..jA+3
    const int jB = 64 + tx * 4;   // outs jB..jB+3  (split keeps LDS reads 2-way)

    int gn[4];
    #pragma unroll
    for (int i = 0; i < 4; i++) {
        int g = n0 + n4 + i;
        gn[i] = (g < n_nodes) ? g : (n_nodes - 1);
    }

    float acc[4][8];   // [node][out]  (0..3 -> jA+q, 4..7 -> jB+q)

    auto relu_acc = [&]() {
        #pragma unroll
        for (int i = 0; i < 4; i++)
            #pragma unroll
            for (int q = 0; q < 8; q++) acc[i][q] = fmaxf(acc[i][q], 0.0f);
    };

    auto lnorm = [&](const float* __restrict__ g, const float* __restrict__ e) {
        float gv[8], ev[8];
        #pragma unroll
        for (int q = 0; q < 8; q++) {
            int j = (q < 4) ? (jA + q) : (jB + q - 4);
            gv[q] = g[j]; ev[q] = e[j];
        }
        #pragma unroll
        for (int i = 0; i < 4; i++) {
            float s1 = 0.f;
            #pragma unroll
            for (int q = 0; q < 8; q++) s1 += acc[i][q];
            #pragma unroll
            for (int m = 1; m < 16; m <<= 1) s1 += __shfl_xor(s1, m);
            float mean = s1 * (1.0f / 128.0f);
            float s2 = 0.f;
            #pragma unroll
            for (int q = 0; q < 8; q++) { float d = acc[i][q] - mean; s2 += d * d; }
            #pragma unroll
            for (int m = 1; m < 16; m <<= 1) s2 += __shfl_xor(s2, m);
            float inv = rsqrtf(s2 * (1.0f / 128.0f) + 1e-5f);
            #pragma unroll
            for (int q = 0; q < 8; q++)
                acc[i][q] = (acc[i][q] - mean) * inv * gv[q] + ev[q];
        }
    };

    auto store_h = [&](int dst) {
        #pragma unroll
        for (int q = 0; q < 4; q++) {
            float4 vA = make_float4(acc[0][q], acc[1][q], acc[2][q], acc[3][q]);
            *(float4*)&hbuf[dst][jA + q][n4] = vA;
            float4 vB = make_float4(acc[0][4 + q], acc[1][4 + q], acc[2][4 + q], acc[3][4 + q]);
            *(float4*)&hbuf[dst][jB + q][n4] = vB;
        }
    };

    auto loadW = [&](const float* __restrict__ W, int nfloats) {
        __syncthreads();
        const float4* src = (const float4*)W;
        float4* dst = (float4*)wl;
        int nv = nfloats >> 2;
        for (int i = t; i < nv; i += 256) dst[i] = src[i];
        __syncthreads();
    };

    auto layer128 = [&](const float* __restrict__ b, int src) {
        #pragma unroll
        for (int q = 0; q < 4; q++) {
            float bA = b[jA + q], bB = b[jB + q];
            #pragma unroll
            for (int i = 0; i < 4; i++) { acc[i][q] = bA; acc[i][4 + q] = bB; }
        }
        #pragma unroll 4
        for (int k = 0; k < 128; k++) {
            float4 a  = *(const float4*)&hbuf[src][k][n4];
            float4 wA = *(const float4*)&wl[k * 128 + jA];
            float4 wB = *(const float4*)&wl[k * 128 + jB];
            float av[4] = {a.x, a.y, a.z, a.w};
            #pragma unroll
            for (int i = 0; i < 4; i++) {
                float v = av[i];
                acc[i][0] += v * wA.x; acc[i][1] += v * wA.y;
                acc[i][2] += v * wA.z; acc[i][3] += v * wA.w;
                acc[i][4] += v * wB.x; acc[i][5] += v * wB.y;
                acc[i][6] += v * wB.z; acc[i][7] += v * wB.w;
            }
        }
    };

    // ---- layer 0: 2 -> 128, relu, LN ----
    {
        float c0[4], c1[4];
        #pragma unroll
        for (int i = 0; i < 4; i++) { c0[i] = coords[gn[i] * 2]; c1[i] = coords[gn[i] * 2 + 1]; }
        #pragma unroll
        for (int q = 0; q < 8; q++) {
            int j = (q < 4) ? (jA + q) : (jB + q - 4);
            float w0 = fw0[j], w1 = fw0[128 + j], b = fb0[j];
            #pragma unroll
            for (int i = 0; i < 4; i++)
                acc[i][q] = fmaxf(c0[i] * w0 + c1[i] * w1 + b, 0.0f);
        }
        lnorm(fg0, fe0);
        store_h(0);
    }

    // ---- layers 1..3: 128 -> 128 ----
    loadW(fw1, 128 * 128);
    layer128(fb1, 0); relu_acc(); lnorm(fg1, fe1); store_h(1);

    loadW(fw2, 128 * 128);
    layer128(fb2, 1); relu_acc(); lnorm(fg2, fe2); store_h(0);

    loadW(fw3, 128 * 128);
    layer128(fb3, 0); relu_acc(); store_h(1);

    // ---- decoder D0: 128 -> 64, tanh ----
    float dacc[4][4];
    {
        loadW(dw0, 128 * 64);
        const int jD = tx * 4;
        #pragma unroll
        for (int q = 0; q < 4; q++) {
            float b = db0[jD + q];
            #pragma unroll
            for (int i = 0; i < 4; i++) dacc[i][q] = b;
        }
        #pragma unroll 4
        for (int k = 0; k < 128; k++) {
            float4 a = *(const float4*)&hbuf[1][k][n4];
            float4 w = *(const float4*)&wl[k * 64 + jD];
            float av[4] = {a.x, a.y, a.z, a.w};
            float wv[4] = {w.x, w.y, w.z, w.w};
            #pragma unroll
            for (int i = 0; i < 4; i++)
                #pragma unroll
                for (int q = 0; q < 4; q++) dacc[i][q] += av[i] * wv[q];
        }
        #pragma unroll
        for (int i = 0; i < 4; i++)
            #pragma unroll
            for (int q = 0; q < 4; q++) dacc[i][q] = tanhf(dacc[i][q]);
        #pragma unroll
        for (int q = 0; q < 4; q++) {
            float4 v = make_float4(dacc[0][q], dacc[1][q], dacc[2][q], dacc[3][q]);
            *(float4*)&hbuf[0][jD + q][n4] = v;
        }
    }

    // ---- decoder D1: 64 -> 32, tanh ----
    float e1[4][2];
    {
        loadW(dw1, 64 * 32);
        const int jD = tx * 2;
        float b0v = db1[jD], b1v = db1[jD + 1];
        #pragma unroll
        for (int i = 0; i < 4; i++) { e1[i][0] = b0v; e1[i][1] = b1v; }
        #pragma unroll 4
        for (int k = 0; k < 64; k++) {
            float4 a = *(const float4*)&hbuf[0][k][n4];
            float2 w = *(const float2*)&wl[k * 32 + jD];
            float av[4] = {a.x, a.y, a.z, a.w};
            #pragma unroll
            for (int i = 0; i < 4; i++) { e1[i][0] += av[i] * w.x; e1[i][1] += av[i] * w.y; }
        }
        #pragma unroll
        for (int i = 0; i < 4; i++) { e1[i][0] = tanhf(e1[i][0]); e1[i][1] = tanhf(e1[i][1]); }
        #pragma unroll
        for (int q = 0; q < 2; q++) {
            float4 v = make_float4(e1[0][q], e1[1][q], e1[2][q], e1[3][q]);
            *(float4*)&hbuf[1][jD + q][n4] = v;
        }
    }

    // ---- decoder D2: 32 -> 16, linear ----
    {
        loadW(dw2, 32 * 16);
        float e2[4];
        float b = db2[tx];
        #pragma unroll
        for (int i = 0; i < 4; i++) e2[i] = b;
        #pragma unroll 4
        for (int k = 0; k < 32; k++) {
            float4 a = *(const float4*)&hbuf[1][k][n4];
            float w = wl[k * 16 + tx];
            float av[4] = {a.x, a.y, a.z, a.w};
            #pragma unroll
            for (int i = 0; i < 4; i++) e2[i] += av[i] * w;
        }
        float4 v = make_float4(e2[0], e2[1], e2[2], e2[3]);
        *(float4*)&hbuf[0][tx][n4] = v;   // emb rows 0..15 in buf 0
    }
    __syncthreads();

    // ---- write x = [features(3), emb(16)] ----
    for (int idx = t; idx < TM * 19; idx += 256) {
        int n = idx / 19, j = idx - n * 19;
        int g = n0 + n;
        if (g < n_nodes) {
            float v = (j < 3) ? features[g * 3 + j] : hbuf[0][j - 3][n];
            xout[(size_t)g * 19 + j] = v;
        }
    }
}

// ---------------- graph kernels ----------------
__global__ void deg_kernel(const int* __restrict__ row, int* __restrict__ cnt, int E_) {
    int e = blockIdx.x * blockDim.x + threadIdx.x;
    if (e < E_) atomicAdd(&cnt[row[e]], 1);
}

__global__ void dinv_kernel(const int* __restrict__ cnt, float* __restrict__ dinv, int n) {
    int i = blockIdx.x * blockDim.x + threadIdx.x;
    if (i < n) dinv[i] = rsqrtf((float)cnt[i] + 1.0f);
}

// conv1 edge aggregation on the 19-dim input x (pre-matmul aggregation)
__global__ void agg1_kernel(const int* __restrict__ row, const int* __restrict__ col,
                            const float* __restrict__ dinv, const float* __restrict__ x,
                            float* __restrict__ agg, int E_) {
    int e = blockIdx.x * blockDim.x + threadIdx.x;
    if (e >= E_) return;
    int r = row[e], c = col[e];
    float nrm = dinv[r] * dinv[c];
    const float* xc = x + (size_t)c * 19;
    float* ar = agg + (size_t)r * 19;
    #pragma unroll
    for (int j = 0; j < 19; j++) unsafeAtomicAdd(&ar[j], xc[j] * nrm);
}

// w_eff = cw2 @ ow (64), b_eff = cb2 @ ow + ob  (folds conv2 matmul + fc)
__global__ void prep_kernel(const float* __restrict__ cw2, const float* __restrict__ cb2,
                            const float* __restrict__ ow, const float* __restrict__ ob,
                            float* __restrict__ wb) {
    int i = threadIdx.x;
    if (i < 64) {
        float a = 0.f;
        for (int j = 0; j < 64; j++) a += cw2[i * 64 + j] * ow[j];
        wb[i] = a;
    }
    if (i == 0) {
        float bb = 0.f;
        for (int j = 0; j < 64; j++) bb += cb2[j] * ow[j];
        wb[64] = bb + ob[0];
    }
}

// per-node: h1 = relu((agg + x*dinv^2) @ cw1 + cb1); s = h1 . w_eff
__global__ __launch_bounds__(256) void node1_kernel(
    const float* __restrict__ agg, const float* __restrict__ x,
    const float* __restrict__ dinv,
    const float* __restrict__ cw1, const float* __restrict__ cb1,
    const float* __restrict__ wb, float* __restrict__ s, int n) {
    __shared__ float w[19 * 64];
    __shared__ float bbs[64];
    __shared__ float wes[64];
    for (int i = threadIdx.x; i < 19 * 64; i += 256) w[i] = cw1[i];
    if (threadIdx.x < 64) { bbs[threadIdx.x] = cb1[threadIdx.x]; wes[threadIdx.x] = wb[threadIdx.x]; }
    __syncthreads();
    int i = blockIdx.x * 256 + threadIdx.x;
    if (i >= n) return;
    float di = dinv[i];
    float d2 = di * di;
    float in19[19];
    #pragma unroll
    for (int k = 0; k < 19; k++)
        in19[k] = agg[(size_t)i * 19 + k] + x[(size_t)i * 19 + k] * d2;
    float a[64];
    #pragma unroll
    for (int j = 0; j < 64; j++) a[j] = bbs[j];
    #pragma unroll
    for (int k = 0; k < 19; k++) {
        float v = in19[k];
        #pragma unroll
        for (int j = 0; j < 64; j++) a[j] += v * w[k * 64 + j];
    }
    float sv = 0.f;
    #pragma unroll
    for (int j = 0; j < 64; j++) sv += fmaxf(a[j], 0.0f) * wes[j];
    s[i] = sv;
}

__global__ void outinit_kernel(const float* __restrict__ s, const float* __restrict__ dinv,
                               const float* __restrict__ wb, float* __restrict__ out, int n) {
    int i = blockIdx.x * blockDim.x + threadIdx.x;
    if (i < n) out[i] = wb[64] + dinv[i] * dinv[i] * s[i];
}

__global__ void agg2_kernel(const int* __restrict__ row, const int* __restrict__ col,
                            const float* __restrict__ dinv, const float* __restrict__ s,
                            float* __restrict__ out, int E_) {
    int e = blockIdx.x * blockDim.x + threadIdx.x;
    if (e >= E_) return;
    int r = row[e], c = col[e];
    unsafeAtomicAdd(&out[r], dinv[r] * dinv[c] * s[c]);
}

extern "C" void kernel_launch(void* const* d_in, const int* in_sizes, int n_in,
                              void* d_out, int out_size, void* d_ws, size_t ws_size,
                              hipStream_t stream) {
    const float* coords   = (const float*)d_in[0];
    const float* features = (const float*)d_in[1];
    const int*   eidx     = (const int*)d_in[2];
    const float* fw0 = (const float*)d_in[3];
    const float* fb0 = (const float*)d_in[4];
    const float* fg0 = (const float*)d_in[5];
    const float* fe0 = (const float*)d_in[6];
    const float* fw1 = (const float*)d_in[7];
    const float* fb1 = (const float*)d_in[8];
    const float* fg1 = (const float*)d_in[9];
    const float* fe1 = (const float*)d_in[10];
    const float* fw2 = (const float*)d_in[11];
    const float* fb2 = (const float*)d_in[12];
    const float* fg2 = (const float*)d_in[13];
    const float* fe2 = (const float*)d_in[14];
    const float* fw3 = (const float*)d_in[15];
    const float* fb3 = (const float*)d_in[16];
    const float* dw0 = (const float*)d_in[17];
    const float* db0 = (const float*)d_in[18];
    const float* dw1 = (const float*)d_in[19];
    const float* db1 = (const float*)d_in[20];
    const float* dw2 = (const float*)d_in[21];
    const float* db2 = (const float*)d_in[22];
    const float* cw1 = (const float*)d_in[23];
    const float* cb1 = (const float*)d_in[24];
    const float* cw2 = (const float*)d_in[25];
    const float* cb2 = (const float*)d_in[26];
    const float* ow  = (const float*)d_in[27];
    const float* ob  = (const float*)d_in[28];
    float* out = (float*)d_out;

    const int Nn = in_sizes[0] / 2;   // 100000
    const int E_ = in_sizes[2] / 2;   // 2000000

    char* ws = (char*)d_ws;
    size_t o = 0;
    float* x    = (float*)(ws + o); o += (size_t)Nn * 19 * sizeof(float);
    float* agg  = (float*)(ws + o); o += (size_t)Nn * 19 * sizeof(float);
    int*   cnt  = (int*)  (ws + o); o += (size_t)Nn * sizeof(int);
    float* dinv = (float*)(ws + o); o += (size_t)Nn * sizeof(float);
    float* s    = (float*)(ws + o); o += (size_t)Nn * sizeof(float);
    float* wb   = (float*)(ws + o); o += 65 * sizeof(float);

    hipMemsetAsync(cnt, 0, (size_t)Nn * sizeof(int), stream);
    hipMemsetAsync(agg, 0, (size_t)Nn * 19 * sizeof(float), stream);

    ffn_kernel<<<(Nn + TM - 1) / TM, 256, 0, stream>>>(
        coords, features,
        fw0, fb0, fg0, fe0, fw1, fb1, fg1, fe1, fw2, fb2, fg2, fe2, fw3, fb3,
        dw0, db0, dw1, db1, dw2, db2, x, Nn);

    deg_kernel<<<(E_ + 255) / 256, 256, 0, stream>>>(eidx, cnt, E_);
    dinv_kernel<<<(Nn + 255) / 256, 256, 0, stream>>>(cnt, dinv, Nn);
    agg1_kernel<<<(E_ + 255) / 256, 256, 0, stream>>>(eidx, eidx + E_, dinv, x, agg, E_);
    prep_kernel<<<1, 64, 0, stream>>>(cw2, cb2, ow, ob, wb);
    node1_kernel<<<(Nn + 255) / 256, 256, 0, stream>>>(agg, x, dinv, cw1, cb1, wb, s, Nn);
    outinit_kernel<<<(Nn + 255) / 256, 256, 0, stream>>>(s, dinv, wb, out, Nn);
    agg2_kernel<<<(E_ + 255) / 256, 256, 0, stream>>>(eidx, eidx + E_, dinv, s, out, E_);
}

// Round 2
// 719.494 us; speedup vs baseline: 3.5407x; 3.5407x over previous
//
#include <hip/hip_runtime.h>
#include <hip/hip_bf16.h>
#include <math.h>

#define TM 64
#define XP 20   // padded x row stride (16B-aligned rows)

// ---------------- fused FFN + decoder: coords -> emb, writes x = [features, emb, 0pad] ----------------
__global__ __launch_bounds__(256) void ffn_kernel(
    const float* __restrict__ coords, const float* __restrict__ features,
    const float* __restrict__ fw0, const float* __restrict__ fb0,
    const float* __restrict__ fg0, const float* __restrict__ fe0,
    const float* __restrict__ fw1, const float* __restrict__ fb1,
    const float* __restrict__ fg1, const float* __restrict__ fe1,
    const float* __restrict__ fw2, const float* __restrict__ fb2,
    const float* __restrict__ fg2, const float* __restrict__ fe2,
    const float* __restrict__ fw3, const float* __restrict__ fb3,
    const float* __restrict__ dw0, const float* __restrict__ db0,
    const float* __restrict__ dw1, const float* __restrict__ db1,
    const float* __restrict__ dw2, const float* __restrict__ db2,
    float* __restrict__ xout, int n_nodes)
{
    __shared__ float hbuf[2][128][TM];   // [feature][node], ping-pong, 64 KB
    __shared__ float wl[128 * 128];      // staged layer weights, 64 KB

    const int t  = threadIdx.x;
    const int tx = t & 15;   // 16 out-groups
    const int ty = t >> 4;   // 16 node-groups of 4
    const int n4 = ty * 4;
    const int n0 = blockIdx.x * TM;

    const int jA = tx * 4;        // outs jA..jA+3
    const int jB = 64 + tx * 4;   // outs jB..jB+3

    int gn[4];
    #pragma unroll
    for (int i = 0; i < 4; i++) {
        int g = n0 + n4 + i;
        gn[i] = (g < n_nodes) ? g : (n_nodes - 1);
    }

    float acc[4][8];

    auto relu_acc = [&]() {
        #pragma unroll
        for (int i = 0; i < 4; i++)
            #pragma unroll
            for (int q = 0; q < 8; q++) acc[i][q] = fmaxf(acc[i][q], 0.0f);
    };

    auto lnorm = [&](const float* __restrict__ g, const float* __restrict__ e) {
        float gv[8], ev[8];
        #pragma unroll
        for (int q = 0; q < 8; q++) {
            int j = (q < 4) ? (jA + q) : (jB + q - 4);
            gv[q] = g[j]; ev[q] = e[j];
        }
        #pragma unroll
        for (int i = 0; i < 4; i++) {
            float s1 = 0.f;
            #pragma unroll
            for (int q = 0; q < 8; q++) s1 += acc[i][q];
            #pragma unroll
            for (int m = 1; m < 16; m <<= 1) s1 += __shfl_xor(s1, m);
            float mean = s1 * (1.0f / 128.0f);
            float s2 = 0.f;
            #pragma unroll
            for (int q = 0; q < 8; q++) { float d = acc[i][q] - mean; s2 += d * d; }
            #pragma unroll
            for (int m = 1; m < 16; m <<= 1) s2 += __shfl_xor(s2, m);
            float inv = rsqrtf(s2 * (1.0f / 128.0f) + 1e-5f);
            #pragma unroll
            for (int q = 0; q < 8; q++)
                acc[i][q] = (acc[i][q] - mean) * inv * gv[q] + ev[q];
        }
    };

    auto store_h = [&](int dst) {
        #pragma unroll
        for (int q = 0; q < 4; q++) {
            float4 vA = make_float4(acc[0][q], acc[1][q], acc[2][q], acc[3][q]);
            *(float4*)&hbuf[dst][jA + q][n4] = vA;
            float4 vB = make_float4(acc[0][4 + q], acc[1][4 + q], acc[2][4 + q], acc[3][4 + q]);
            *(float4*)&hbuf[dst][jB + q][n4] = vB;
        }
    };

    auto loadW = [&](const float* __restrict__ W, int nfloats) {
        __syncthreads();
        const float4* src = (const float4*)W;
        float4* dst = (float4*)wl;
        int nv = nfloats >> 2;
        for (int i = t; i < nv; i += 256) dst[i] = src[i];
        __syncthreads();
    };

    auto layer128 = [&](const float* __restrict__ b, int src) {
        #pragma unroll
        for (int q = 0; q < 4; q++) {
            float bA = b[jA + q], bB = b[jB + q];
            #pragma unroll
            for (int i = 0; i < 4; i++) { acc[i][q] = bA; acc[i][4 + q] = bB; }
        }
        #pragma unroll 4
        for (int k = 0; k < 128; k++) {
            float4 a  = *(const float4*)&hbuf[src][k][n4];
            float4 wA = *(const float4*)&wl[k * 128 + jA];
            float4 wB = *(const float4*)&wl[k * 128 + jB];
            float av[4] = {a.x, a.y, a.z, a.w};
            #pragma unroll
            for (int i = 0; i < 4; i++) {
                float v = av[i];
                acc[i][0] += v * wA.x; acc[i][1] += v * wA.y;
                acc[i][2] += v * wA.z; acc[i][3] += v * wA.w;
                acc[i][4] += v * wB.x; acc[i][5] += v * wB.y;
                acc[i][6] += v * wB.z; acc[i][7] += v * wB.w;
            }
        }
    };

    // ---- layer 0: 2 -> 128, relu, LN ----
    {
        float c0[4], c1[4];
        #pragma unroll
        for (int i = 0; i < 4; i++) { c0[i] = coords[gn[i] * 2]; c1[i] = coords[gn[i] * 2 + 1]; }
        #pragma unroll
        for (int q = 0; q < 8; q++) {
            int j = (q < 4) ? (jA + q) : (jB + q - 4);
            float w0 = fw0[j], w1 = fw0[128 + j], b = fb0[j];
            #pragma unroll
            for (int i = 0; i < 4; i++)
                acc[i][q] = fmaxf(c0[i] * w0 + c1[i] * w1 + b, 0.0f);
        }
        lnorm(fg0, fe0);
        store_h(0);
    }

    // ---- layers 1..3: 128 -> 128 ----
    loadW(fw1, 128 * 128);
    layer128(fb1, 0); relu_acc(); lnorm(fg1, fe1); store_h(1);

    loadW(fw2, 128 * 128);
    layer128(fb2, 1); relu_acc(); lnorm(fg2, fe2); store_h(0);

    loadW(fw3, 128 * 128);
    layer128(fb3, 0); relu_acc(); store_h(1);

    // ---- decoder D0: 128 -> 64, tanh ----
    float dacc[4][4];
    {
        loadW(dw0, 128 * 64);
        const int jD = tx * 4;
        #pragma unroll
        for (int q = 0; q < 4; q++) {
            float b = db0[jD + q];
            #pragma unroll
            for (int i = 0; i < 4; i++) dacc[i][q] = b;
        }
        #pragma unroll 4
        for (int k = 0; k < 128; k++) {
            float4 a = *(const float4*)&hbuf[1][k][n4];
            float4 w = *(const float4*)&wl[k * 64 + jD];
            float av[4] = {a.x, a.y, a.z, a.w};
            float wv[4] = {w.x, w.y, w.z, w.w};
            #pragma unroll
            for (int i = 0; i < 4; i++)
                #pragma unroll
                for (int q = 0; q < 4; q++) dacc[i][q] += av[i] * wv[q];
        }
        #pragma unroll
        for (int i = 0; i < 4; i++)
            #pragma unroll
            for (int q = 0; q < 4; q++) dacc[i][q] = tanhf(dacc[i][q]);
        #pragma unroll
        for (int q = 0; q < 4; q++) {
            float4 v = make_float4(dacc[0][q], dacc[1][q], dacc[2][q], dacc[3][q]);
            *(float4*)&hbuf[0][jD + q][n4] = v;
        }
    }

    // ---- decoder D1: 64 -> 32, tanh ----
    float e1[4][2];
    {
        loadW(dw1, 64 * 32);
        const int jD = tx * 2;
        float b0v = db1[jD], b1v = db1[jD + 1];
        #pragma unroll
        for (int i = 0; i < 4; i++) { e1[i][0] = b0v; e1[i][1] = b1v; }
        #pragma unroll 4
        for (int k = 0; k < 64; k++) {
            float4 a = *(const float4*)&hbuf[0][k][n4];
            float2 w = *(const float2*)&wl[k * 32 + jD];
            float av[4] = {a.x, a.y, a.z, a.w};
            #pragma unroll
            for (int i = 0; i < 4; i++) { e1[i][0] += av[i] * w.x; e1[i][1] += av[i] * w.y; }
        }
        #pragma unroll
        for (int i = 0; i < 4; i++) { e1[i][0] = tanhf(e1[i][0]); e1[i][1] = tanhf(e1[i][1]); }
        #pragma unroll
        for (int q = 0; q < 2; q++) {
            float4 v = make_float4(e1[0][q], e1[1][q], e1[2][q], e1[3][q]);
            *(float4*)&hbuf[1][jD + q][n4] = v;
        }
    }

    // ---- decoder D2: 32 -> 16, linear ----
    {
        loadW(dw2, 32 * 16);
        float e2[4];
        float b = db2[tx];
        #pragma unroll
        for (int i = 0; i < 4; i++) e2[i] = b;
        #pragma unroll 4
        for (int k = 0; k < 32; k++) {
            float4 a = *(const float4*)&hbuf[1][k][n4];
            float w = wl[k * 16 + tx];
            float av[4] = {a.x, a.y, a.z, a.w};
            #pragma unroll
            for (int i = 0; i < 4; i++) e2[i] += av[i] * w;
        }
        float4 v = make_float4(e2[0], e2[1], e2[2], e2[3]);
        *(float4*)&hbuf[0][tx][n4] = v;   // emb rows 0..15 in buf 0
    }
    __syncthreads();

    // ---- write x = [features(3), emb(16), pad0] stride XP=20 ----
    for (int idx = t; idx < TM * XP; idx += 256) {
        int n = idx / XP, j = idx - n * XP;
        int g = n0 + n;
        if (g < n_nodes) {
            float v = (j < 3) ? features[g * 3 + j] : (j < 19 ? hbuf[0][j - 3][n] : 0.0f);
            xout[(size_t)g * XP + j] = v;
        }
    }
}

// ---------------- CSR build ----------------
__global__ void deg_kernel(const int* __restrict__ row, int* __restrict__ cnt, int E_) {
    int e = blockIdx.x * blockDim.x + threadIdx.x;
    if (e < E_) atomicAdd(&cnt[row[e]], 1);
}

// exclusive scan: per-block scan + block sums
__global__ void scan1_kernel(const int* __restrict__ cnt, int* __restrict__ offs,
                             int* __restrict__ bsum, int n) {
    __shared__ int tmp[256];
    int t = threadIdx.x, b = blockIdx.x, i = b * 256 + t;
    int v = (i < n) ? cnt[i] : 0;
    tmp[t] = v; __syncthreads();
    #pragma unroll
    for (int d = 1; d < 256; d <<= 1) {
        int add = (t >= d) ? tmp[t - d] : 0;
        __syncthreads();
        tmp[t] += add;
        __syncthreads();
    }
    if (i < n) offs[i] = tmp[t] - v;
    if (t == 255) bsum[b] = tmp[t];
}

__global__ void scan2_kernel(int* __restrict__ bsum, int B) {
    __shared__ int tmp[512];
    int t = threadIdx.x;
    tmp[t] = (t < B) ? bsum[t] : 0; __syncthreads();
    #pragma unroll
    for (int d = 1; d < 512; d <<= 1) {
        int add = (t >= d) ? tmp[t - d] : 0;
        __syncthreads();
        tmp[t] += add;
        __syncthreads();
    }
    if (t < B) bsum[t] = tmp[t];
}

// finalize offs, init fill, compute dinv
__global__ void scan3_kernel(int* __restrict__ offs, const int* __restrict__ bsum,
                             const int* __restrict__ cnt, int* __restrict__ fill,
                             float* __restrict__ dinv, int n) {
    int i = blockIdx.x * blockDim.x + threadIdx.x;
    if (i >= n) return;
    int b = i >> 8;
    int base = (b > 0) ? bsum[b - 1] : 0;
    int o = offs[i] + base;
    offs[i] = o;
    fill[i] = o;
    dinv[i] = rsqrtf((float)cnt[i] + 1.0f);
}

__global__ void scatter_kernel(const int* __restrict__ row, const int* __restrict__ col,
                               int* __restrict__ fill, int* __restrict__ es, int E_) {
    int e = blockIdx.x * blockDim.x + threadIdx.x;
    if (e >= E_) return;
    int r = row[e];
    int p = atomicAdd(&fill[r], 1);
    es[p] = col[e];
}

// w_eff = cw2 @ ow (64), b_eff = cb2 @ ow + ob
__global__ void prep_kernel(const float* __restrict__ cw2, const float* __restrict__ cb2,
                            const float* __restrict__ ow, const float* __restrict__ ob,
                            float* __restrict__ wb) {
    int i = threadIdx.x;
    if (i < 64) {
        float a = 0.f;
        for (int j = 0; j < 64; j++) a += cw2[i * 64 + j] * ow[j];
        wb[i] = a;
    }
    if (i == 0) {
        float bb = 0.f;
        for (int j = 0; j < 64; j++) bb += cb2[j] * ow[j];
        wb[64] = bb + ob[0];
    }
}

// per-node: gather-aggregate x over CSR neighbors, matmul 20x64, relu, dot w_eff -> s[i]
__global__ __launch_bounds__(256) void node1g_kernel(
    const int* __restrict__ offs, const int* __restrict__ cnt, const int* __restrict__ es,
    const float* __restrict__ dinv, const float* __restrict__ x,
    const float* __restrict__ cw1, const float* __restrict__ cb1,
    const float* __restrict__ wb, float* __restrict__ s, int n)
{
    __shared__ float w[XP * 64];
    __shared__ float bbs[64];
    __shared__ float wes[64];
    for (int i = threadIdx.x; i < 19 * 64; i += 256) w[i] = cw1[i];
    for (int i = threadIdx.x; i < 64; i += 256) {
        w[19 * 64 + i] = 0.0f;        // pad row
        bbs[i] = cb1[i];
        wes[i] = wb[i];
    }
    __syncthreads();
    int i = blockIdx.x * 256 + threadIdx.x;
    if (i >= n) return;
    float di = dinv[i];
    float d2 = di * di;

    float a19[XP];
    {
        const float4* xi = (const float4*)(x + (size_t)i * XP);
        #pragma unroll
        for (int q = 0; q < 5; q++) {
            float4 v = xi[q];
            a19[q * 4 + 0] = v.x * d2; a19[q * 4 + 1] = v.y * d2;
            a19[q * 4 + 2] = v.z * d2; a19[q * 4 + 3] = v.w * d2;
        }
    }
    int st = offs[i], dg = cnt[i];
    for (int e = 0; e < dg; e++) {
        int c = es[st + e];
        float nm = di * dinv[c];
        const float4* xc = (const float4*)(x + (size_t)c * XP);
        #pragma unroll
        for (int q = 0; q < 5; q++) {
            float4 v = xc[q];
            a19[q * 4 + 0] += v.x * nm; a19[q * 4 + 1] += v.y * nm;
            a19[q * 4 + 2] += v.z * nm; a19[q * 4 + 3] += v.w * nm;
        }
    }

    float a[64];
    #pragma unroll
    for (int j = 0; j < 64; j++) a[j] = bbs[j];
    #pragma unroll
    for (int k = 0; k < 19; k++) {
        float v = a19[k];
        #pragma unroll
        for (int j = 0; j < 64; j++) a[j] += v * w[k * 64 + j];
    }
    float sv = 0.f;
    #pragma unroll
    for (int j = 0; j < 64; j++) sv += fmaxf(a[j], 0.0f) * wes[j];
    s[i] = sv;
}

// per-node: out[i] = b_eff + d2*s[i] + di * sum over neighbors dinv[c]*s[c]
__global__ __launch_bounds__(256) void outg_kernel(
    const int* __restrict__ offs, const int* __restrict__ cnt, const int* __restrict__ es,
    const float* __restrict__ dinv, const float* __restrict__ s,
    const float* __restrict__ wb, float* __restrict__ out, int n)
{
    int i = blockIdx.x * 256 + threadIdx.x;
    if (i >= n) return;
    float di = dinv[i];
    float sum = 0.f;
    int st = offs[i], dg = cnt[i];
    for (int e = 0; e < dg; e++) {
        int c = es[st + e];
        sum += dinv[c] * s[c];
    }
    out[i] = wb[64] + di * di * s[i] + di * sum;
}

extern "C" void kernel_launch(void* const* d_in, const int* in_sizes, int n_in,
                              void* d_out, int out_size, void* d_ws, size_t ws_size,
                              hipStream_t stream) {
    const float* coords   = (const float*)d_in[0];
    const float* features = (const float*)d_in[1];
    const int*   eidx     = (const int*)d_in[2];
    const float* fw0 = (const float*)d_in[3];
    const float* fb0 = (const float*)d_in[4];
    const float* fg0 = (const float*)d_in[5];
    const float* fe0 = (const float*)d_in[6];
    const float* fw1 = (const float*)d_in[7];
    const float* fb1 = (const float*)d_in[8];
    const float* fg1 = (const float*)d_in[9];
    const float* fe1 = (const float*)d_in[10];
    const float* fw2 = (const float*)d_in[11];
    const float* fb2 = (const float*)d_in[12];
    const float* fg2 = (const float*)d_in[13];
    const float* fe2 = (const float*)d_in[14];
    const float* fw3 = (const float*)d_in[15];
    const float* fb3 = (const float*)d_in[16];
    const float* dw0 = (const float*)d_in[17];
    const float* db0 = (const float*)d_in[18];
    const float* dw1 = (const float*)d_in[19];
    const float* db1 = (const float*)d_in[20];
    const float* dw2 = (const float*)d_in[21];
    const float* db2 = (const float*)d_in[22];
    const float* cw1 = (const float*)d_in[23];
    const float* cb1 = (const float*)d_in[24];
    const float* cw2 = (const float*)d_in[25];
    const float* cb2 = (const float*)d_in[26];
    const float* ow  = (const float*)d_in[27];
    const float* ob  = (const float*)d_in[28];
    float* out = (float*)d_out;

    const int Nn = in_sizes[0] / 2;   // 100000
    const int E_ = in_sizes[2] / 2;   // 2000000
    const int NB = (Nn + 255) / 256;  // scan blocks (<=512)

    char* ws = (char*)d_ws;
    size_t o = 0;
    float* x    = (float*)(ws + o); o += (size_t)Nn * XP * sizeof(float);
    int*   cnt  = (int*)  (ws + o); o += (size_t)Nn * sizeof(int);
    int*   offs = (int*)  (ws + o); o += (size_t)Nn * sizeof(int);
    int*   fill = (int*)  (ws + o); o += (size_t)Nn * sizeof(int);
    int*   bsum = (int*)  (ws + o); o += 512 * sizeof(int);
    float* dinv = (float*)(ws + o); o += (size_t)Nn * sizeof(float);
    float* s    = (float*)(ws + o); o += (size_t)Nn * sizeof(float);
    int*   es   = (int*)  (ws + o); o += (size_t)E_ * sizeof(int);
    float* wb   = (float*)(ws + o); o += 80 * sizeof(float);

    hipMemsetAsync(cnt, 0, (size_t)Nn * sizeof(int), stream);

    ffn_kernel<<<(Nn + TM - 1) / TM, 256, 0, stream>>>(
        coords, features,
        fw0, fb0, fg0, fe0, fw1, fb1, fg1, fe1, fw2, fb2, fg2, fe2, fw3, fb3,
        dw0, db0, dw1, db1, dw2, db2, x, Nn);

    deg_kernel<<<(E_ + 255) / 256, 256, 0, stream>>>(eidx, cnt, E_);
    scan1_kernel<<<NB, 256, 0, stream>>>(cnt, offs, bsum, Nn);
    scan2_kernel<<<1, 512, 0, stream>>>(bsum, NB);
    scan3_kernel<<<NB, 256, 0, stream>>>(offs, bsum, cnt, fill, dinv, Nn);
    scatter_kernel<<<(E_ + 255) / 256, 256, 0, stream>>>(eidx, eidx + E_, fill, es, E_);
    prep_kernel<<<1, 64, 0, stream>>>(cw2, cb2, ow, ob, wb);
    node1g_kernel<<<NB, 256, 0, stream>>>(offs, cnt, es, dinv, x, cw1, cb1, wb, s, Nn);
    outg_kernel<<<NB, 256, 0, stream>>>(offs, cnt, es, dinv, s, wb, out, Nn);
}

// Round 3
// 542.225 us; speedup vs baseline: 4.6983x; 1.3269x over previous
//
#include <hip/hip_runtime.h>
#include <hip/hip_bf16.h>
#include <math.h>

#define TM 64
#define XP 20   // padded x row stride (16B-aligned rows)

// ---------------- fused FFN + decoder: coords -> emb, writes x = [features, emb, 0pad] ----------------
// Mapping: lane = node (64 nodes/block), wave = output-feature slice.
// All weight addresses are wave-uniform (readfirstlane) -> s_load scalar broadcasts.
// All LDS accesses are hbuf[feat][lane] -> conflict-free.
__global__ __launch_bounds__(256) void ffn_kernel(
    const float* __restrict__ coords, const float* __restrict__ features,
    const float* __restrict__ fw0, const float* __restrict__ fb0,
    const float* __restrict__ fg0, const float* __restrict__ fe0,
    const float* __restrict__ fw1, const float* __restrict__ fb1,
    const float* __restrict__ fg1, const float* __restrict__ fe1,
    const float* __restrict__ fw2, const float* __restrict__ fb2,
    const float* __restrict__ fg2, const float* __restrict__ fe2,
    const float* __restrict__ fw3, const float* __restrict__ fb3,
    const float* __restrict__ dw0, const float* __restrict__ db0,
    const float* __restrict__ dw1, const float* __restrict__ db1,
    const float* __restrict__ dw2, const float* __restrict__ db2,
    float* __restrict__ xout, int n_nodes)
{
    __shared__ float hbuf[128][64];   // [feature][node], 32 KB
    __shared__ float ps1[4][64];      // LN partial sums
    __shared__ float ps2[4][64];      // LN partial sumsq

    const int t    = threadIdx.x;
    const int lane = t & 63;
    const int w    = __builtin_amdgcn_readfirstlane(t >> 6);  // wave id, SGPR
    const int jw   = w * 32;                                   // this wave's 32 outs
    const int n0   = blockIdx.x * TM;

    int g = n0 + lane;
    if (g >= n_nodes) g = n_nodes - 1;

    float acc[32];

    // LN over 128 feats: per-wave register partials + cross-wave LDS combine
    auto lnorm = [&](const float* __restrict__ gam, const float* __restrict__ bet) {
        float s1 = 0.f, s2 = 0.f;
        #pragma unroll
        for (int q = 0; q < 32; q++) { s1 += acc[q]; s2 += acc[q] * acc[q]; }
        ps1[w][lane] = s1; ps2[w][lane] = s2;
        __syncthreads();
        float t1 = ps1[0][lane] + ps1[1][lane] + ps1[2][lane] + ps1[3][lane];
        float t2 = ps2[0][lane] + ps2[1][lane] + ps2[2][lane] + ps2[3][lane];
        float mean = t1 * (1.0f / 128.0f);
        float var  = t2 * (1.0f / 128.0f) - mean * mean;
        float inv  = rsqrtf(var + 1e-5f);
        #pragma unroll
        for (int q = 0; q < 32; q++) {
            int j = jw + q;
            acc[q] = (acc[q] - mean) * inv * gam[j] + bet[j];   // gam/bet: uniform s_loads
        }
    };

    auto store32 = [&]() {
        #pragma unroll
        for (int q = 0; q < 32; q++) hbuf[jw + q][lane] = acc[q];
    };

    // 128 -> 128 matmul: acc[q] = b[jw+q] + sum_k hbuf[k][lane] * W[k][jw+q]
    auto layer128 = [&](const float* __restrict__ W, const float* __restrict__ b) {
        #pragma unroll
        for (int q = 0; q < 32; q++) acc[q] = b[jw + q];
        #pragma unroll 4
        for (int k = 0; k < 128; k++) {
            float av = hbuf[k][lane];
            const float4* W4 = (const float4*)(W + k * 128 + jw);  // uniform -> s_load_dwordx4
            #pragma unroll
            for (int q8 = 0; q8 < 8; q8++) {
                float4 wv = W4[q8];
                acc[q8 * 4 + 0] += av * wv.x;
                acc[q8 * 4 + 1] += av * wv.y;
                acc[q8 * 4 + 2] += av * wv.z;
                acc[q8 * 4 + 3] += av * wv.w;
            }
        }
    };

    // ---- layer 0: 2 -> 128, relu, LN ----
    {
        float2 c = *(const float2*)&coords[(size_t)g * 2];
        #pragma unroll
        for (int q = 0; q < 32; q++) {
            int j = jw + q;
            acc[q] = fmaxf(c.x * fw0[j] + c.y * fw0[128 + j] + fb0[j], 0.0f);
        }
        lnorm(fg0, fe0);
        store32();
        __syncthreads();
    }

    // ---- layers 1..2: 128 -> 128, relu, LN ----
    layer128(fw1, fb1);
    #pragma unroll
    for (int q = 0; q < 32; q++) acc[q] = fmaxf(acc[q], 0.0f);
    lnorm(fg1, fe1);           // internal barrier covers WAR on hbuf
    store32();
    __syncthreads();

    layer128(fw2, fb2);
    #pragma unroll
    for (int q = 0; q < 32; q++) acc[q] = fmaxf(acc[q], 0.0f);
    lnorm(fg2, fe2);
    store32();
    __syncthreads();

    // ---- layer 3: 128 -> 128, relu only ----
    layer128(fw3, fb3);
    #pragma unroll
    for (int q = 0; q < 32; q++) acc[q] = fmaxf(acc[q], 0.0f);
    __syncthreads();           // all reads of hbuf done before overwrite
    store32();
    __syncthreads();

    // ---- decoder D0: 128 -> 64, tanh ----
    {
        const int j16 = w * 16;
        float d0[16];
        #pragma unroll
        for (int q = 0; q < 16; q++) d0[q] = db0[j16 + q];
        #pragma unroll 4
        for (int k = 0; k < 128; k++) {
            float av = hbuf[k][lane];
            const float4* W4 = (const float4*)(dw0 + k * 64 + j16);
            #pragma unroll
            for (int q4 = 0; q4 < 4; q4++) {
                float4 wv = W4[q4];
                d0[q4 * 4 + 0] += av * wv.x;
                d0[q4 * 4 + 1] += av * wv.y;
                d0[q4 * 4 + 2] += av * wv.z;
                d0[q4 * 4 + 3] += av * wv.w;
            }
        }
        #pragma unroll
        for (int q = 0; q < 16; q++) d0[q] = tanhf(d0[q]);
        __syncthreads();
        #pragma unroll
        for (int q = 0; q < 16; q++) hbuf[j16 + q][lane] = d0[q];
        __syncthreads();
    }

    // ---- decoder D1: 64 -> 32, tanh ----
    {
        const int j8 = w * 8;
        float d1[8];
        #pragma unroll
        for (int q = 0; q < 8; q++) d1[q] = db1[j8 + q];
        #pragma unroll 4
        for (int k = 0; k < 64; k++) {
            float av = hbuf[k][lane];
            const float4* W4 = (const float4*)(dw1 + k * 32 + j8);
            #pragma unroll
            for (int q4 = 0; q4 < 2; q4++) {
                float4 wv = W4[q4];
                d1[q4 * 4 + 0] += av * wv.x;
                d1[q4 * 4 + 1] += av * wv.y;
                d1[q4 * 4 + 2] += av * wv.z;
                d1[q4 * 4 + 3] += av * wv.w;
            }
        }
        #pragma unroll
        for (int q = 0; q < 8; q++) d1[q] = tanhf(d1[q]);
        __syncthreads();
        #pragma unroll
        for (int q = 0; q < 8; q++) hbuf[j8 + q][lane] = d1[q];
        __syncthreads();
    }

    // ---- decoder D2: 32 -> 16, linear ----
    {
        const int j4 = w * 4;
        float d2[4];
        #pragma unroll
        for (int q = 0; q < 4; q++) d2[q] = db2[j4 + q];
        #pragma unroll 4
        for (int k = 0; k < 32; k++) {
            float av = hbuf[k][lane];
            const float4* W4 = (const float4*)(dw2 + k * 16 + j4);
            float4 wv = W4[0];
            d2[0] += av * wv.x; d2[1] += av * wv.y;
            d2[2] += av * wv.z; d2[3] += av * wv.w;
        }
        __syncthreads();
        #pragma unroll
        for (int q = 0; q < 4; q++) hbuf[j4 + q][lane] = d2[q];
        __syncthreads();
    }

    // ---- write x = [features(3), emb(16), pad0] stride XP=20 ----
    for (int idx = t; idx < TM * XP; idx += 256) {
        int n = idx / XP, j = idx - n * XP;
        int gg = n0 + n;
        if (gg < n_nodes) {
            float v = (j < 3) ? features[gg * 3 + j] : (j < 19 ? hbuf[j - 3][n] : 0.0f);
            xout[(size_t)gg * XP + j] = v;
        }
    }
}

// ---------------- CSR build ----------------
__global__ void deg_kernel(const int* __restrict__ row, int* __restrict__ cnt, int E_) {
    int e = blockIdx.x * blockDim.x + threadIdx.x;
    if (e < E_) atomicAdd(&cnt[row[e]], 1);
}

// exclusive scan: per-block scan + block sums
__global__ void scan1_kernel(const int* __restrict__ cnt, int* __restrict__ offs,
                             int* __restrict__ bsum, int n) {
    __shared__ int tmp[256];
    int t = threadIdx.x, b = blockIdx.x, i = b * 256 + t;
    int v = (i < n) ? cnt[i] : 0;
    tmp[t] = v; __syncthreads();
    #pragma unroll
    for (int d = 1; d < 256; d <<= 1) {
        int add = (t >= d) ? tmp[t - d] : 0;
        __syncthreads();
        tmp[t] += add;
        __syncthreads();
    }
    if (i < n) offs[i] = tmp[t] - v;
    if (t == 255) bsum[b] = tmp[t];
}

__global__ void scan2_kernel(int* __restrict__ bsum, int B) {
    __shared__ int tmp[512];
    int t = threadIdx.x;
    tmp[t] = (t < B) ? bsum[t] : 0; __syncthreads();
    #pragma unroll
    for (int d = 1; d < 512; d <<= 1) {
        int add = (t >= d) ? tmp[t - d] : 0;
        __syncthreads();
        tmp[t] += add;
        __syncthreads();
    }
    if (t < B) bsum[t] = tmp[t];
}

// finalize offs, init fill, compute dinv
__global__ void scan3_kernel(int* __restrict__ offs, const int* __restrict__ bsum,
                             const int* __restrict__ cnt, int* __restrict__ fill,
                             float* __restrict__ dinv, int n) {
    int i = blockIdx.x * blockDim.x + threadIdx.x;
    if (i >= n) return;
    int b = i >> 8;
    int base = (b > 0) ? bsum[b - 1] : 0;
    int o = offs[i] + base;
    offs[i] = o;
    fill[i] = o;
    dinv[i] = rsqrtf((float)cnt[i] + 1.0f);
}

__global__ void scatter_kernel(const int* __restrict__ row, const int* __restrict__ col,
                               int* __restrict__ fill, int* __restrict__ es, int E_) {
    int e = blockIdx.x * blockDim.x + threadIdx.x;
    if (e >= E_) return;
    int r = row[e];
    int p = atomicAdd(&fill[r], 1);
    es[p] = col[e];
}

// w_eff = cw2 @ ow (64), b_eff = cb2 @ ow + ob
__global__ void prep_kernel(const float* __restrict__ cw2, const float* __restrict__ cb2,
                            const float* __restrict__ ow, const float* __restrict__ ob,
                            float* __restrict__ wb) {
    int i = threadIdx.x;
    if (i < 64) {
        float a = 0.f;
        for (int j = 0; j < 64; j++) a += cw2[i * 64 + j] * ow[j];
        wb[i] = a;
    }
    if (i == 0) {
        float bb = 0.f;
        for (int j = 0; j < 64; j++) bb += cb2[j] * ow[j];
        wb[64] = bb + ob[0];
    }
}

// per-node: gather-aggregate x over CSR neighbors, matmul 20x64, relu, dot w_eff -> s[i]
__global__ __launch_bounds__(256) void node1g_kernel(
    const int* __restrict__ offs, const int* __restrict__ cnt, const int* __restrict__ es,
    const float* __restrict__ dinv, const float* __restrict__ x,
    const float* __restrict__ cw1, const float* __restrict__ cb1,
    const float* __restrict__ wb, float* __restrict__ s, int n)
{
    __shared__ float w[XP * 64];
    __shared__ float bbs[64];
    __shared__ float wes[64];
    for (int i = threadIdx.x; i < 19 * 64; i += 256) w[i] = cw1[i];
    for (int i = threadIdx.x; i < 64; i += 256) {
        w[19 * 64 + i] = 0.0f;        // pad row
        bbs[i] = cb1[i];
        wes[i] = wb[i];
    }
    __syncthreads();
    int i = blockIdx.x * 256 + threadIdx.x;
    if (i >= n) return;
    float di = dinv[i];
    float d2 = di * di;

    float a19[XP];
    {
        const float4* xi = (const float4*)(x + (size_t)i * XP);
        #pragma unroll
        for (int q = 0; q < 5; q++) {
            float4 v = xi[q];
            a19[q * 4 + 0] = v.x * d2; a19[q * 4 + 1] = v.y * d2;
            a19[q * 4 + 2] = v.z * d2; a19[q * 4 + 3] = v.w * d2;
        }
    }
    int st = offs[i], dg = cnt[i];
    for (int e = 0; e < dg; e++) {
        int c = es[st + e];
        float nm = di * dinv[c];
        const float4* xc = (const float4*)(x + (size_t)c * XP);
        #pragma unroll
        for (int q = 0; q < 5; q++) {
            float4 v = xc[q];
            a19[q * 4 + 0] += v.x * nm; a19[q * 4 + 1] += v.y * nm;
            a19[q * 4 + 2] += v.z * nm; a19[q * 4 + 3] += v.w * nm;
        }
    }

    float a[64];
    #pragma unroll
    for (int j = 0; j < 64; j++) a[j] = bbs[j];
    #pragma unroll
    for (int k = 0; k < 19; k++) {
        float v = a19[k];
        #pragma unroll
        for (int j = 0; j < 64; j++) a[j] += v * w[k * 64 + j];
    }
    float sv = 0.f;
    #pragma unroll
    for (int j = 0; j < 64; j++) sv += fmaxf(a[j], 0.0f) * wes[j];
    s[i] = sv;
}

// per-node: out[i] = b_eff + d2*s[i] + di * sum over neighbors dinv[c]*s[c]
__global__ __launch_bounds__(256) void outg_kernel(
    const int* __restrict__ offs, const int* __restrict__ cnt, const int* __restrict__ es,
    const float* __restrict__ dinv, const float* __restrict__ s,
    const float* __restrict__ wb, float* __restrict__ out, int n)
{
    int i = blockIdx.x * 256 + threadIdx.x;
    if (i >= n) return;
    float di = dinv[i];
    float sum = 0.f;
    int st = offs[i], dg = cnt[i];
    for (int e = 0; e < dg; e++) {
        int c = es[st + e];
        sum += dinv[c] * s[c];
    }
    out[i] = wb[64] + di * di * s[i] + di * sum;
}

extern "C" void kernel_launch(void* const* d_in, const int* in_sizes, int n_in,
                              void* d_out, int out_size, void* d_ws, size_t ws_size,
                              hipStream_t stream) {
    const float* coords   = (const float*)d_in[0];
    const float* features = (const float*)d_in[1];
    const int*   eidx     = (const int*)d_in[2];
    const float* fw0 = (const float*)d_in[3];
    const float* fb0 = (const float*)d_in[4];
    const float* fg0 = (const float*)d_in[5];
    const float* fe0 = (const float*)d_in[6];
    const float* fw1 = (const float*)d_in[7];
    const float* fb1 = (const float*)d_in[8];
    const float* fg1 = (const float*)d_in[9];
    const float* fe1 = (const float*)d_in[10];
    const float* fw2 = (const float*)d_in[11];
    const float* fb2 = (const float*)d_in[12];
    const float* fg2 = (const float*)d_in[13];
    const float* fe2 = (const float*)d_in[14];
    const float* fw3 = (const float*)d_in[15];
    const float* fb3 = (const float*)d_in[16];
    const float* dw0 = (const float*)d_in[17];
    const float* db0 = (const float*)d_in[18];
    const float* dw1 = (const float*)d_in[19];
    const float* db1 = (const float*)d_in[20];
    const float* dw2 = (const float*)d_in[21];
    const float* db2 = (const float*)d_in[22];
    const float* cw1 = (const float*)d_in[23];
    const float* cb1 = (const float*)d_in[24];
    const float* cw2 = (const float*)d_in[25];
    const float* cb2 = (const float*)d_in[26];
    const float* ow  = (const float*)d_in[27];
    const float* ob  = (const float*)d_in[28];
    float* out = (float*)d_out;

    const int Nn = in_sizes[0] / 2;   // 100000
    const int E_ = in_sizes[2] / 2;   // 2000000
    const int NB = (Nn + 255) / 256;  // scan blocks (<=512)

    char* ws = (char*)d_ws;
    size_t o = 0;
    float* x    = (float*)(ws + o); o += (size_t)Nn * XP * sizeof(float);
    int*   cnt  = (int*)  (ws + o); o += (size_t)Nn * sizeof(int);
    int*   offs = (int*)  (ws + o); o += (size_t)Nn * sizeof(int);
    int*   fill = (int*)  (ws + o); o += (size_t)Nn * sizeof(int);
    int*   bsum = (int*)  (ws + o); o += 512 * sizeof(int);
    float* dinv = (float*)(ws + o); o += (size_t)Nn * sizeof(float);
    float* s    = (float*)(ws + o); o += (size_t)Nn * sizeof(float);
    int*   es   = (int*)  (ws + o); o += (size_t)E_ * sizeof(int);
    float* wb   = (float*)(ws + o); o += 80 * sizeof(float);

    hipMemsetAsync(cnt, 0, (size_t)Nn * sizeof(int), stream);

    ffn_kernel<<<(Nn + TM - 1) / TM, 256, 0, stream>>>(
        coords, features,
        fw0, fb0, fg0, fe0, fw1, fb1, fg1, fe1, fw2, fb2, fg2, fe2, fw3, fb3,
        dw0, db0, dw1, db1, dw2, db2, x, Nn);

    deg_kernel<<<(E_ + 255) / 256, 256, 0, stream>>>(eidx, cnt, E_);
    scan1_kernel<<<NB, 256, 0, stream>>>(cnt, offs, bsum, Nn);
    scan2_kernel<<<1, 512, 0, stream>>>(bsum, NB);
    scan3_kernel<<<NB, 256, 0, stream>>>(offs, bsum, cnt, fill, dinv, Nn);
    scatter_kernel<<<(E_ + 255) / 256, 256, 0, stream>>>(eidx, eidx + E_, fill, es, E_);
    prep_kernel<<<1, 64, 0, stream>>>(cw2, cb2, ow, ob, wb);
    node1g_kernel<<<NB, 256, 0, stream>>>(offs, cnt, es, dinv, x, cw1, cb1, wb, s, Nn);
    outg_kernel<<<NB, 256, 0, stream>>>(offs, cnt, es, dinv, s, wb, out, Nn);
}